// Round 1
// baseline (191.851 us; speedup 1.0000x reference)
//
#include <hip/hip_runtime.h>
#include <hip/hip_bf16.h>
#include <math.h>

// Problem constants
#define Bc 4
#define Nc 1024
#define Ec 1024
#define Hc 16
#define Dc 64
#define Mc 4096              // B*N rows
#define BHc 64               // B*H heads
#define OUT0_ELEMS 4194304   // B*H*N*D

typedef __attribute__((ext_vector_type(4))) float f32x4;
typedef __attribute__((ext_vector_type(8))) short s16x8;

__device__ __forceinline__ short f2bf(float f) {
    union { float f; unsigned u; } c; c.f = f;
    unsigned r = c.u + 0x7fffu + ((c.u >> 16) & 1u);   // round-to-nearest-even
    return (short)(r >> 16);
}

// ---------------------------------------------------------------------------
// Projection GEMM: out = X @ W^T + b   (X: 4096x1024 fp32 row-major,
// W: 1024x1024 fp32 row-major -> NT GEMM, both operands row-major along K)
// sel 0 -> Q (bf16 to ws), 1 -> K (bf16 to ws), 2 -> V (fp32 to d_out)
// Output layout: [b][h][n][d]  (head-split)
// ---------------------------------------------------------------------------
__global__ __launch_bounds__(256, 2)
void proj_kernel(const float* __restrict__ q, const float* __restrict__ k,
                 const float* __restrict__ v, const float* __restrict__ Wq,
                 const float* __restrict__ Wk, const float* __restrict__ Wv,
                 const float* __restrict__ bq, const float* __restrict__ bk,
                 const float* __restrict__ bv,
                 short* __restrict__ qws, short* __restrict__ kws,
                 float* __restrict__ vout)
{
    const int sel = blockIdx.z;
    const float* X    = (sel == 0) ? q  : (sel == 1) ? k  : v;
    const float* W    = (sel == 0) ? Wq : (sel == 1) ? Wk : Wv;
    const float* bias = (sel == 0) ? bq : (sel == 1) ? bk : bv;

    // LDS tiles, 128 rows x 32 bf16, padded to stride 40 (80B = 20 banks)
    __shared__ __align__(16) short lA[128 * 40];
    __shared__ __align__(16) short lB[128 * 40];

    const int t    = threadIdx.x;
    const int lane = t & 63;
    const int w    = t >> 6;
    const int wr   = w >> 1, wc = w & 1;     // 2x2 wave grid, each 64x64
    const int li   = lane & 15, g = lane >> 4;
    const int bm   = blockIdx.x * 128;
    const int bn   = blockIdx.y * 128;

    const int srow = t >> 1;                 // staging: row 0..127
    const int skh  = t & 1;                  // staging: k-half (16 floats)

    f32x4 acc[4][4];
#pragma unroll
    for (int i = 0; i < 4; ++i)
#pragma unroll
        for (int j = 0; j < 4; ++j)
            acc[i][j] = (f32x4){0.f, 0.f, 0.f, 0.f};

    for (int kt = 0; kt < 32; ++kt) {
        // ---- stage A and B tiles (fp32 -> bf16) ----
        {
            const float* sa = X + (size_t)(bm + srow) * Ec + kt * 32 + skh * 16;
            const float* sb = W + (size_t)(bn + srow) * Ec + kt * 32 + skh * 16;
            f32x4 a0 = *(const f32x4*)(sa);
            f32x4 a1 = *(const f32x4*)(sa + 4);
            f32x4 a2 = *(const f32x4*)(sa + 8);
            f32x4 a3 = *(const f32x4*)(sa + 12);
            f32x4 b0 = *(const f32x4*)(sb);
            f32x4 b1 = *(const f32x4*)(sb + 4);
            f32x4 b2 = *(const f32x4*)(sb + 8);
            f32x4 b3 = *(const f32x4*)(sb + 12);
            s16x8 ha0, ha1, hb0, hb1;
#pragma unroll
            for (int i = 0; i < 4; ++i) {
                ha0[i]     = f2bf(a0[i]);
                ha0[i + 4] = f2bf(a1[i]);
                ha1[i]     = f2bf(a2[i]);
                ha1[i + 4] = f2bf(a3[i]);
                hb0[i]     = f2bf(b0[i]);
                hb0[i + 4] = f2bf(b1[i]);
                hb1[i]     = f2bf(b2[i]);
                hb1[i + 4] = f2bf(b3[i]);
            }
            const int base = srow * 40 + skh * 16;
            *(s16x8*)&lA[base]     = ha0;
            *(s16x8*)&lA[base + 8] = ha1;
            *(s16x8*)&lB[base]     = hb0;
            *(s16x8*)&lB[base + 8] = hb1;
        }
        __syncthreads();

        // ---- MFMA on the tile (one K=32 step) ----
        s16x8 aF[4], bF[4];
#pragma unroll
        for (int mt = 0; mt < 4; ++mt)
            aF[mt] = *(const s16x8*)&lA[(wr * 64 + mt * 16 + li) * 40 + g * 8];
#pragma unroll
        for (int nt = 0; nt < 4; ++nt)
            bF[nt] = *(const s16x8*)&lB[(wc * 64 + nt * 16 + li) * 40 + g * 8];
#pragma unroll
        for (int mt = 0; mt < 4; ++mt)
#pragma unroll
            for (int nt = 0; nt < 4; ++nt)
                acc[mt][nt] = __builtin_amdgcn_mfma_f32_16x16x32_bf16(
                    aF[mt], bF[nt], acc[mt][nt], 0, 0, 0);
        __syncthreads();
    }

    // ---- epilogue: bias add + head-split scatter ----
    short* dstBF = (sel == 0) ? qws : kws;
#pragma unroll
    for (int nt = 0; nt < 4; ++nt) {
        const int col = bn + wc * 64 + nt * 16 + li;
        const float bcol = bias[col];
        const int h = col >> 6, d = col & 63;
#pragma unroll
        for (int mt = 0; mt < 4; ++mt) {
#pragma unroll
            for (int r = 0; r < 4; ++r) {
                const int row = bm + wr * 64 + mt * 16 + g * 4 + r;
                const int bb = row >> 10, n = row & 1023;
                const size_t off =
                    ((size_t)(bb * Hc + h) * Nc + n) * Dc + d;
                const float val = acc[mt][nt][r] + bcol;
                if (sel == 2)
                    vout[off] = val;
                else
                    dstBF[off] = f2bf(val);
            }
        }
    }
}

// ---------------------------------------------------------------------------
// Scores + softmax: for each (head, 16-row block) compute S = Q Kt / 32,
// softmax over the full 1024-wide row (exact, single pass: whole row block
// lives in the block's registers), write fp32 attn.
// 4 waves; wave w owns columns [256w, 256w+256).
// ---------------------------------------------------------------------------
__global__ __launch_bounds__(256, 2)
void attn_kernel(const short* __restrict__ qws, const short* __restrict__ kws,
                 float* __restrict__ attnOut)
{
    const int rb = blockIdx.x;   // 0..63  (16-row block)
    const int bh = blockIdx.y;   // 0..63  (b*H + h)
    const int t  = threadIdx.x;
    const int w  = t >> 6;
    const int lane = t & 63;
    const int li = lane & 15, g = lane >> 4;

    const short* Qb = qws + (size_t)bh * (Nc * Dc);
    const short* Kb = kws + (size_t)bh * (Nc * Dc);

    // Q fragments for this block's 16 rows (shared by all waves)
    s16x8 qF[2];
    {
        const short* qp = Qb + (size_t)(rb * 16 + li) * Dc + g * 8;
        qF[0] = *(const s16x8*)(qp);
        qF[1] = *(const s16x8*)(qp + 32);
    }

    f32x4 acc[16];
#pragma unroll
    for (int i = 0; i < 16; ++i) acc[i] = (f32x4){0.f, 0.f, 0.f, 0.f};

    const int colbase = w * 256;
#pragma unroll
    for (int ct = 0; ct < 16; ++ct) {
        const short* kp = Kb + (size_t)(colbase + ct * 16 + li) * Dc + g * 8;
        s16x8 k0 = *(const s16x8*)(kp);
        s16x8 k1 = *(const s16x8*)(kp + 32);
        acc[ct] = __builtin_amdgcn_mfma_f32_16x16x32_bf16(qF[0], k0, acc[ct], 0, 0, 0);
        acc[ct] = __builtin_amdgcn_mfma_f32_16x16x32_bf16(qF[1], k1, acc[ct], 0, 0, 0);
    }

    // ---- row max (exact softmax; rows are g*4+r within the 16-row block) ----
    float mx[4];
#pragma unroll
    for (int r = 0; r < 4; ++r) {
        float m = acc[0][r];
#pragma unroll
        for (int ct = 1; ct < 16; ++ct) m = fmaxf(m, acc[ct][r]);
#pragma unroll
        for (int off = 1; off < 16; off <<= 1)
            m = fmaxf(m, __shfl_xor(m, off));
        mx[r] = m;
    }

    __shared__ float red[4][16];
    if (li == 0) {
#pragma unroll
        for (int r = 0; r < 4; ++r) red[w][g * 4 + r] = mx[r];
    }
    __syncthreads();
#pragma unroll
    for (int r = 0; r < 4; ++r) {
        float m = red[0][g * 4 + r];
#pragma unroll
        for (int w2 = 1; w2 < 4; ++w2) m = fmaxf(m, red[w2][g * 4 + r]);
        mx[r] = m;
    }
    __syncthreads();

    // ---- exp + row sum ----
    const float inv = 1.0f / 32.0f;   // SCALE = sqrt(E) = 32
    float sm[4] = {0.f, 0.f, 0.f, 0.f};
#pragma unroll
    for (int ct = 0; ct < 16; ++ct) {
#pragma unroll
        for (int r = 0; r < 4; ++r) {
            float p = __expf((acc[ct][r] - mx[r]) * inv);
            acc[ct][r] = p;
            sm[r] += p;
        }
    }
#pragma unroll
    for (int r = 0; r < 4; ++r) {
#pragma unroll
        for (int off = 1; off < 16; off <<= 1)
            sm[r] += __shfl_xor(sm[r], off);
    }
    if (li == 0) {
#pragma unroll
        for (int r = 0; r < 4; ++r) red[w][g * 4 + r] = sm[r];
    }
    __syncthreads();
#pragma unroll
    for (int r = 0; r < 4; ++r) {
        float s = red[0][g * 4 + r] + red[1][g * 4 + r] +
                  red[2][g * 4 + r] + red[3][g * 4 + r];
        sm[r] = 1.0f / s;
    }

    // ---- write normalized attn ----
    float* outp = attnOut + (size_t)bh * (Nc * Nc);
#pragma unroll
    for (int ct = 0; ct < 16; ++ct) {
        const int col = colbase + ct * 16 + li;
#pragma unroll
        for (int r = 0; r < 4; ++r) {
            const int row = rb * 16 + g * 4 + r;
            outp[(size_t)row * Nc + col] = acc[ct][r] * sm[r];
        }
    }
}

extern "C" void kernel_launch(void* const* d_in, const int* in_sizes, int n_in,
                              void* d_out, int out_size, void* d_ws, size_t ws_size,
                              hipStream_t stream) {
    const float* q  = (const float*)d_in[0];
    const float* k  = (const float*)d_in[1];
    const float* v  = (const float*)d_in[2];
    const float* Wq = (const float*)d_in[3];
    const float* bq = (const float*)d_in[4];
    const float* Wk = (const float*)d_in[5];
    const float* bk = (const float*)d_in[6];
    const float* Wv = (const float*)d_in[7];
    const float* bv = (const float*)d_in[8];

    float* out0 = (float*)d_out;                      // (B,H,N,D) fp32
    float* attn = (float*)d_out + OUT0_ELEMS;         // (B,H,N,N) fp32

    short* qws = (short*)d_ws;                        // bf16 Q [b][h][n][d]
    short* kws = qws + (size_t)Mc * Ec;               // bf16 K [b][h][n][d]

    proj_kernel<<<dim3(32, 8, 3), 256, 0, stream>>>(
        q, k, v, Wq, Wk, Wv, bq, bk, bv, qws, kws, out0);
    attn_kernel<<<dim3(64, 64), 256, 0, stream>>>(qws, kws, attn);
}

// Round 2
// 161.921 us; speedup vs baseline: 1.1848x; 1.1848x over previous
//
#include <hip/hip_runtime.h>
#include <hip/hip_bf16.h>
#include <math.h>

// Problem constants
#define Bc 4
#define Nc 1024
#define Ec 1024
#define Hc 16
#define Dc 64
#define Mc 4096              // B*N rows
#define OUT0_ELEMS 4194304   // B*H*N*D

typedef __attribute__((ext_vector_type(4))) float f32x4;
typedef __attribute__((ext_vector_type(8))) short s16x8;
typedef __attribute__((ext_vector_type(4))) short s16x4;

// Hardware bf16 convert: compiler pairs these into v_cvt_pk_bf16_f32.
__device__ __forceinline__ short f2bf(float f) {
    union { __bf16 h; short s; } c;
    c.h = (__bf16)f;
    return c.s;
}
__device__ __forceinline__ s16x4 pk4(const f32x4 v) {
    s16x4 r;
    r[0] = f2bf(v[0]); r[1] = f2bf(v[1]); r[2] = f2bf(v[2]); r[3] = f2bf(v[3]);
    return r;
}

// ---------------------------------------------------------------------------
// Projection GEMM: out = X @ W^T + b  (X: 4096x1024 fp32, W: 1024x1024 fp32,
// both row-major along K -> NT GEMM). sel 0 -> Q (bf16 ws), 1 -> K (bf16 ws),
// 2 -> V (fp32 to d_out). Output layout head-split [b][h][n][d].
// 128x128 tile, BK=64, 4 waves (2x2 of 64x64), reg-prefetch pipeline.
// ---------------------------------------------------------------------------
__global__ __launch_bounds__(256, 2)
void proj_kernel(const float* __restrict__ q, const float* __restrict__ k,
                 const float* __restrict__ v, const float* __restrict__ Wq,
                 const float* __restrict__ Wk, const float* __restrict__ Wv,
                 const float* __restrict__ bq, const float* __restrict__ bk,
                 const float* __restrict__ bv,
                 short* __restrict__ qws, short* __restrict__ kws,
                 float* __restrict__ vout)
{
    const int sel = blockIdx.z;
    const float* X    = (sel == 0) ? q  : (sel == 1) ? k  : v;
    const float* W    = (sel == 0) ? Wq : (sel == 1) ? Wk : Wv;
    const float* bias = (sel == 0) ? bq : (sel == 1) ? bk : bv;

    // 128 rows x 64 bf16, padded to stride 72 shorts (144B -> 2-way-free reads)
    __shared__ __align__(16) short lA[128 * 72];
    __shared__ __align__(16) short lB[128 * 72];

    const int t    = threadIdx.x;
    const int lane = t & 63;
    const int w    = t >> 6;
    const int wr   = w >> 1, wc = w & 1;     // 2x2 wave grid, each 64x64
    const int li   = lane & 15, g = lane >> 4;
    const int bm   = blockIdx.x * 128;
    const int bn   = blockIdx.y * 128;

    // staging: instruction j covers rows [j*16, j*16+16), 16 lanes x 16B = 256B/row
    const int srow = t >> 4;                 // 0..15
    const int scol = (t & 15) * 4;           // float col within 64-wide slice

    const float* Xb = X + (size_t)bm * Ec;
    const float* Wb = W + (size_t)bn * Ec;

    f32x4 rA[8], rB[8];
    // prologue: loads for kt=0
#pragma unroll
    for (int j = 0; j < 8; ++j) {
        const int r = j * 16 + srow;
        rA[j] = *(const f32x4*)(Xb + (size_t)r * Ec + scol);
        rB[j] = *(const f32x4*)(Wb + (size_t)r * Ec + scol);
    }

    f32x4 acc[4][4];
#pragma unroll
    for (int i = 0; i < 4; ++i)
#pragma unroll
        for (int j = 0; j < 4; ++j)
            acc[i][j] = (f32x4){0.f, 0.f, 0.f, 0.f};

    for (int kt = 0; kt < 16; ++kt) {
        // ---- convert + write LDS (consumes rA/rB) ----
#pragma unroll
        for (int j = 0; j < 8; ++j) {
            const int r = j * 16 + srow;
            *(s16x4*)&lA[r * 72 + scol] = pk4(rA[j]);
            *(s16x4*)&lB[r * 72 + scol] = pk4(rB[j]);
        }
        __syncthreads();

        // ---- prefetch next tile (in flight across the MFMA phase) ----
        if (kt < 15) {
            const int kb = (kt + 1) * 64;
#pragma unroll
            for (int j = 0; j < 8; ++j) {
                const int r = j * 16 + srow;
                rA[j] = *(const f32x4*)(Xb + (size_t)r * Ec + kb + scol);
                rB[j] = *(const f32x4*)(Wb + (size_t)r * Ec + kb + scol);
            }
        }

        // ---- MFMA: two K=32 sub-steps ----
#pragma unroll
        for (int s = 0; s < 2; ++s) {
            s16x8 aF[4], bF[4];
#pragma unroll
            for (int mt = 0; mt < 4; ++mt)
                aF[mt] = *(const s16x8*)&lA[(wr * 64 + mt * 16 + li) * 72 + s * 32 + g * 8];
#pragma unroll
            for (int nt = 0; nt < 4; ++nt)
                bF[nt] = *(const s16x8*)&lB[(wc * 64 + nt * 16 + li) * 72 + s * 32 + g * 8];
#pragma unroll
            for (int mt = 0; mt < 4; ++mt)
#pragma unroll
                for (int nt = 0; nt < 4; ++nt)
                    acc[mt][nt] = __builtin_amdgcn_mfma_f32_16x16x32_bf16(
                        aF[mt], bF[nt], acc[mt][nt], 0, 0, 0);
        }
        __syncthreads();
    }

    // ---- epilogue: bias add + head-split scatter ----
    short* dstBF = (sel == 0) ? qws : kws;
#pragma unroll
    for (int nt = 0; nt < 4; ++nt) {
        const int col = bn + wc * 64 + nt * 16 + li;
        const float bcol = bias[col];
        const int h = col >> 6, d = col & 63;
#pragma unroll
        for (int mt = 0; mt < 4; ++mt) {
#pragma unroll
            for (int r = 0; r < 4; ++r) {
                const int row = bm + wr * 64 + mt * 16 + g * 4 + r;
                const int bb = row >> 10, n = row & 1023;
                const size_t off =
                    ((size_t)(bb * Hc + h) * Nc + n) * Dc + d;
                const float val = acc[mt][nt][r] + bcol;
                if (sel == 2)
                    vout[off] = val;
                else
                    dstBF[off] = f2bf(val);
            }
        }
    }
}

// ---------------------------------------------------------------------------
// Scores + softmax (unchanged structure): each block = (head, 16-row block),
// 4 waves each own 256 columns, exact single-pass softmax, fp32 attn write.
// ---------------------------------------------------------------------------
__global__ __launch_bounds__(256, 2)
void attn_kernel(const short* __restrict__ qws, const short* __restrict__ kws,
                 float* __restrict__ attnOut)
{
    const int rb = blockIdx.x;   // 0..63  (16-row block)
    const int bh = blockIdx.y;   // 0..63  (b*H + h)
    const int t  = threadIdx.x;
    const int w  = t >> 6;
    const int lane = t & 63;
    const int li = lane & 15, g = lane >> 4;

    const short* Qb = qws + (size_t)bh * (Nc * Dc);
    const short* Kb = kws + (size_t)bh * (Nc * Dc);

    s16x8 qF[2];
    {
        const short* qp = Qb + (size_t)(rb * 16 + li) * Dc + g * 8;
        qF[0] = *(const s16x8*)(qp);
        qF[1] = *(const s16x8*)(qp + 32);
    }

    f32x4 acc[16];
#pragma unroll
    for (int i = 0; i < 16; ++i) acc[i] = (f32x4){0.f, 0.f, 0.f, 0.f};

    const int colbase = w * 256;
#pragma unroll
    for (int ct = 0; ct < 16; ++ct) {
        const short* kp = Kb + (size_t)(colbase + ct * 16 + li) * Dc + g * 8;
        s16x8 k0 = *(const s16x8*)(kp);
        s16x8 k1 = *(const s16x8*)(kp + 32);
        acc[ct] = __builtin_amdgcn_mfma_f32_16x16x32_bf16(qF[0], k0, acc[ct], 0, 0, 0);
        acc[ct] = __builtin_amdgcn_mfma_f32_16x16x32_bf16(qF[1], k1, acc[ct], 0, 0, 0);
    }

    // ---- row max ----
    float mx[4];
#pragma unroll
    for (int r = 0; r < 4; ++r) {
        float m = acc[0][r];
#pragma unroll
        for (int ct = 1; ct < 16; ++ct) m = fmaxf(m, acc[ct][r]);
#pragma unroll
        for (int off = 1; off < 16; off <<= 1)
            m = fmaxf(m, __shfl_xor(m, off));
        mx[r] = m;
    }

    __shared__ float red[4][16];
    if (li == 0) {
#pragma unroll
        for (int r = 0; r < 4; ++r) red[w][g * 4 + r] = mx[r];
    }
    __syncthreads();
#pragma unroll
    for (int r = 0; r < 4; ++r) {
        float m = red[0][g * 4 + r];
#pragma unroll
        for (int w2 = 1; w2 < 4; ++w2) m = fmaxf(m, red[w2][g * 4 + r]);
        mx[r] = m;
    }
    __syncthreads();

    // ---- exp + row sum: p = exp2(s*c - m*c), c = log2(e)/32 ----
    const float c = 1.44269504f / 32.0f;
    float nmc[4];
#pragma unroll
    for (int r = 0; r < 4; ++r) nmc[r] = -mx[r] * c;

    float sm[4] = {0.f, 0.f, 0.f, 0.f};
#pragma unroll
    for (int ct = 0; ct < 16; ++ct) {
#pragma unroll
        for (int r = 0; r < 4; ++r) {
            float p = __builtin_amdgcn_exp2f(fmaf(acc[ct][r], c, nmc[r]));
            acc[ct][r] = p;
            sm[r] += p;
        }
    }
#pragma unroll
    for (int r = 0; r < 4; ++r) {
#pragma unroll
        for (int off = 1; off < 16; off <<= 1)
            sm[r] += __shfl_xor(sm[r], off);
    }
    if (li == 0) {
#pragma unroll
        for (int r = 0; r < 4; ++r) red[w][g * 4 + r] = sm[r];
    }
    __syncthreads();
#pragma unroll
    for (int r = 0; r < 4; ++r) {
        float s = red[0][g * 4 + r] + red[1][g * 4 + r] +
                  red[2][g * 4 + r] + red[3][g * 4 + r];
        sm[r] = 1.0f / s;
    }

    // ---- write normalized attn ----
    float* outp = attnOut + (size_t)bh * (Nc * Nc);
#pragma unroll
    for (int ct = 0; ct < 16; ++ct) {
        const int col = colbase + ct * 16 + li;
#pragma unroll
        for (int r = 0; r < 4; ++r) {
            const int row = rb * 16 + g * 4 + r;
            outp[(size_t)row * Nc + col] = acc[ct][r] * sm[r];
        }
    }
}

extern "C" void kernel_launch(void* const* d_in, const int* in_sizes, int n_in,
                              void* d_out, int out_size, void* d_ws, size_t ws_size,
                              hipStream_t stream) {
    const float* q  = (const float*)d_in[0];
    const float* k  = (const float*)d_in[1];
    const float* v  = (const float*)d_in[2];
    const float* Wq = (const float*)d_in[3];
    const float* bq = (const float*)d_in[4];
    const float* Wk = (const float*)d_in[5];
    const float* bk = (const float*)d_in[6];
    const float* Wv = (const float*)d_in[7];
    const float* bv = (const float*)d_in[8];

    float* out0 = (float*)d_out;                      // (B,H,N,D) fp32
    float* attn = (float*)d_out + OUT0_ELEMS;         // (B,H,N,N) fp32

    short* qws = (short*)d_ws;                        // bf16 Q [b][h][n][d]
    short* kws = qws + (size_t)Mc * Ec;               // bf16 K [b][h][n][d]

    proj_kernel<<<dim3(32, 8, 3), 256, 0, stream>>>(
        q, k, v, Wq, Wk, Wv, bq, bk, bv, qws, kws, out0);
    attn_kernel<<<dim3(64, 64), 256, 0, stream>>>(qws, kws, attn);
}